// Round 1
// baseline (421.669 us; speedup 1.0000x reference)
//
#include <hip/hip_runtime.h>
#include <hip/hip_bf16.h>

#define B_ 4
#define T_ 2048
#define E_ 1024
#define H_ 16
#define HD_ 64

typedef __attribute__((ext_vector_type(8))) short bf16x8;
typedef __attribute__((ext_vector_type(4))) float f32x4;

__device__ inline ushort f2b(float f) {
  union { __hip_bfloat16 h; ushort u; } c;
  c.h = __float2bfloat16(f);
  return c.u;
}
__device__ inline short f2bs(float f) {
  union { __hip_bfloat16 h; short s; } c;
  c.h = __float2bfloat16(f);
  return c.s;
}

// ---------------- W_qkv fp32 [H][HD][192] -> bf16 transposed [H][192][HD] ----
__global__ __launch_bounds__(256) void cvt_w_kernel(const float* __restrict__ Wq,
                                                    ushort* __restrict__ Wt) {
  int gtid = blockIdx.x * 256 + threadIdx.x;   // 0 .. H*HD*192-1 = 196608
  int h = gtid / (HD_ * 192);
  int rem = gtid % (HD_ * 192);
  int d = rem / 192;
  int e = rem % 192;
  Wt[h * (192 * HD_) + e * HD_ + d] = f2b(Wq[gtid]);
}

// ---------------- W_proj fp32 [E][E] -> bf16 [E][E] -------------------------
__global__ __launch_bounds__(256) void cvt_wproj_kernel(const float* __restrict__ Wp,
                                                        ushort* __restrict__ Wb) {
  int i = (blockIdx.x * 256 + threadIdx.x) * 4;
  float4 f = *reinterpret_cast<const float4*>(Wp + i);
  ushort4 u;
  u.x = f2b(f.x); u.y = f2b(f.y); u.z = f2b(f.z); u.w = f2b(f.w);
  *reinterpret_cast<ushort4*>(Wb + i) = u;
}

// ---------------- QKV projection: per-head [64t x 64d] x [64d x 192e] -------
// grid (T/64, B*H), 256 thr (4 waves, 16 t-rows each). MFMA 16x16x32 bf16.
__global__ __launch_bounds__(256) void qkv_kernel(const float* __restrict__ x,
                                                  const ushort* __restrict__ Wt,
                                                  const float* __restrict__ bq,
                                                  ushort* __restrict__ Q,
                                                  ushort* __restrict__ K,
                                                  ushort* __restrict__ V) {
  const float SCALE = 1.0f / (8.0f + 1e-5f);
  int wave = threadIdx.x >> 6, lane = threadIdx.x & 63;
  int lo = lane & 15, hi = lane >> 4;
  int bh = blockIdx.y, b = bh >> 4, h = bh & 15;
  int t0 = blockIdx.x * 64 + wave * 16;

  // A fragments: row = t0+lo, k(=d) = c*32 + hi*8 + j. Convert fp32->bf16 in reg.
  const float* xr = x + (size_t)(b * T_ + t0 + lo) * E_ + h * HD_;
  bf16x8 af[2];
#pragma unroll
  for (int c = 0; c < 2; ++c) {
    float4 f0 = *reinterpret_cast<const float4*>(xr + c * 32 + hi * 8);
    float4 f1 = *reinterpret_cast<const float4*>(xr + c * 32 + hi * 8 + 4);
    bf16x8 v;
    v[0] = f2bs(f0.x); v[1] = f2bs(f0.y); v[2] = f2bs(f0.z); v[3] = f2bs(f0.w);
    v[4] = f2bs(f1.x); v[5] = f2bs(f1.y); v[6] = f2bs(f1.z); v[7] = f2bs(f1.w);
    af[c] = v;
  }

  const ushort* Wh = Wt + h * (192 * HD_);   // [e][d]
#pragma unroll
  for (int nt = 0; nt < 12; ++nt) {
    int n0 = nt * 16;
    bf16x8 bf0 = *reinterpret_cast<const bf16x8*>(Wh + (size_t)(n0 + lo) * HD_ + hi * 8);
    bf16x8 bf1 = *reinterpret_cast<const bf16x8*>(Wh + (size_t)(n0 + lo) * HD_ + 32 + hi * 8);
    f32x4 acc = {0.0f, 0.0f, 0.0f, 0.0f};
    acc = __builtin_amdgcn_mfma_f32_16x16x32_bf16(af[0], bf0, acc, 0, 0, 0);
    acc = __builtin_amdgcn_mfma_f32_16x16x32_bf16(af[1], bf1, acc, 0, 0, 0);

    int which = nt >> 2;                 // 0=Q,1=K,2=V (uniform per tile)
    int hd = (nt & 3) * 16 + lo;
    float bias = bq[h * 192 + n0 + lo];
    ushort* dst = which == 0 ? Q : (which == 1 ? K : V);
    float sc = which == 0 ? SCALE : 1.0f;
#pragma unroll
    for (int r = 0; r < 4; ++r) {
      int t = t0 + hi * 4 + r;
      dst[((size_t)bh * T_ + t) * HD_ + hd] = f2b((acc[r] + bias) * sc);
    }
  }
}

// ---------------- Flash attention (causal) ----------------------------------
// grid (T/64, B*H), 256 thr = 4 waves, each wave owns 16 q-rows.
// Q pre-scaled. Q,K,V bf16 [B,H,T,HD]. Output AO bf16 [B,T,H,HD] (= [B*T,E]).
__global__ __launch_bounds__(256) void attn_kernel(const ushort* __restrict__ Q,
                                                   const ushort* __restrict__ K,
                                                   const ushort* __restrict__ V,
                                                   ushort* __restrict__ AO) {
  __shared__ ushort Plds[4][16][40];   // per-wave P tile [q][key], padded
  int wave = threadIdx.x >> 6, lane = threadIdx.x & 63;
  int lo = lane & 15, hi = lane >> 4;
  int bh = blockIdx.y, b = bh >> 4, h = bh & 15;
  int qw = blockIdx.x * 64 + wave * 16;

  const ushort* Qb = Q + ((size_t)bh * T_ + qw) * HD_;
  bf16x8 qf0 = *reinterpret_cast<const bf16x8*>(Qb + lo * HD_ + hi * 8);
  bf16x8 qf1 = *reinterpret_cast<const bf16x8*>(Qb + lo * HD_ + 32 + hi * 8);

  f32x4 o[4];
#pragma unroll
  for (int n = 0; n < 4; ++n) o[n] = (f32x4){0.0f, 0.0f, 0.0f, 0.0f};
  float m[4] = {-1e30f, -1e30f, -1e30f, -1e30f};
  float l[4] = {0.0f, 0.0f, 0.0f, 0.0f};

  const ushort* Kbh = K + (size_t)bh * T_ * HD_;
  const ushort* Vbh = V + (size_t)bh * T_ * HD_;

  int ntiles = (qw + 47) >> 5;   // keys 0 .. qw+15 covered by 32-key tiles
  for (int tile = 0; tile < ntiles; ++tile) {
    int kt = tile << 5;
    f32x4 s[2];
#pragma unroll
    for (int k2 = 0; k2 < 2; ++k2) {
      const ushort* Kb = Kbh + (size_t)(kt + k2 * 16) * HD_;
      bf16x8 kf0 = *reinterpret_cast<const bf16x8*>(Kb + lo * HD_ + hi * 8);
      bf16x8 kf1 = *reinterpret_cast<const bf16x8*>(Kb + lo * HD_ + 32 + hi * 8);
      f32x4 acc = {0.0f, 0.0f, 0.0f, 0.0f};
      acc = __builtin_amdgcn_mfma_f32_16x16x32_bf16(qf0, kf0, acc, 0, 0, 0);
      acc = __builtin_amdgcn_mfma_f32_16x16x32_bf16(qf1, kf1, acc, 0, 0, 0);
      s[k2] = acc;
    }
    // causal mask: D layout col(key)=lo, row(q)=hi*4+r
#pragma unroll
    for (int k2 = 0; k2 < 2; ++k2) {
      int key = kt + k2 * 16 + lo;
#pragma unroll
      for (int r = 0; r < 4; ++r) {
        int q = qw + hi * 4 + r;
        if (key > q) s[k2][r] = -1e30f;
      }
    }
    // online softmax (row = 16-lane group reduce)
    float alpha[4], ps[2][4];
#pragma unroll
    for (int r = 0; r < 4; ++r) {
      float mx = fmaxf(s[0][r], s[1][r]);
      mx = fmaxf(mx, __shfl_xor(mx, 1));
      mx = fmaxf(mx, __shfl_xor(mx, 2));
      mx = fmaxf(mx, __shfl_xor(mx, 4));
      mx = fmaxf(mx, __shfl_xor(mx, 8));
      float nm = fmaxf(m[r], mx);
      alpha[r] = __expf(m[r] - nm);
      m[r] = nm;
      float p0 = __expf(s[0][r] - nm);
      float p1 = __expf(s[1][r] - nm);
      ps[0][r] = p0; ps[1][r] = p1;
      float rs = p0 + p1;
      rs += __shfl_xor(rs, 1);
      rs += __shfl_xor(rs, 2);
      rs += __shfl_xor(rs, 4);
      rs += __shfl_xor(rs, 8);
      l[r] = l[r] * alpha[r] + rs;
    }
#pragma unroll
    for (int n = 0; n < 4; ++n)
#pragma unroll
      for (int r = 0; r < 4; ++r) o[n][r] *= alpha[r];
    // stage P (bf16) to per-wave LDS: [q=hi*4+r][key=k2*16+lo]
#pragma unroll
    for (int k2 = 0; k2 < 2; ++k2)
#pragma unroll
      for (int r = 0; r < 4; ++r)
        Plds[wave][hi * 4 + r][k2 * 16 + lo] = f2b(ps[k2][r]);
    asm volatile("s_waitcnt lgkmcnt(0)" ::: "memory");
    // P A-fragment: row q=lo, k(=key)=hi*8+j
    bf16x8 pf = *reinterpret_cast<const bf16x8*>(&Plds[wave][lo][hi * 8]);
    // PV: B frag = V[key=hi*8+j][hdcol=n*16+lo] (strided gather)
#pragma unroll
    for (int n = 0; n < 4; ++n) {
      bf16x8 vf;
#pragma unroll
      for (int j = 0; j < 8; ++j)
        vf[j] = (short)Vbh[(size_t)(kt + hi * 8 + j) * HD_ + n * 16 + lo];
      o[n] = __builtin_amdgcn_mfma_f32_16x16x32_bf16(pf, vf, o[n], 0, 0, 0);
    }
  }
  // epilogue: normalize, write AO[b][t][h][hd]
  float inv[4];
#pragma unroll
  for (int r = 0; r < 4; ++r) inv[r] = 1.0f / l[r];
#pragma unroll
  for (int n = 0; n < 4; ++n)
#pragma unroll
    for (int r = 0; r < 4; ++r) {
      int q = qw + hi * 4 + r;
      AO[((size_t)(b * T_ + q) * H_ + h) * HD_ + n * 16 + lo] = f2b(o[n][r] * inv[r]);
    }
}

// ---------------- Output projection: [8192,1024] x [1024,1024]^T + bias -----
// 128x128 tile, BK=32, 4 waves (2x2), each wave 64x64 (4x4 16x16 frags).
__global__ __launch_bounds__(256) void proj_kernel(const ushort* __restrict__ A,
                                                   const ushort* __restrict__ Wb,
                                                   const float* __restrict__ bias,
                                                   float* __restrict__ out) {
  __shared__ ushort As[128][40];
  __shared__ ushort Bs[128][40];
  int tid = threadIdx.x;
  int wave = tid >> 6, lane = tid & 63;
  int lo = lane & 15, hi = lane >> 4;
  int wr = wave >> 1, wc = wave & 1;
  int m0 = blockIdx.y * 128, n0 = blockIdx.x * 128;

  f32x4 acc[4][4] = {};
  for (int k0 = 0; k0 < E_; k0 += 32) {
#pragma unroll
    for (int rep = 0; rep < 2; ++rep) {
      int chunk = rep * 256 + tid;     // 0..511 = 128 rows x 4 16B-chunks
      int row = chunk >> 2, c = chunk & 3;
      *reinterpret_cast<int4*>(&As[row][c * 8]) =
          *reinterpret_cast<const int4*>(A + (size_t)(m0 + row) * E_ + k0 + c * 8);
      *reinterpret_cast<int4*>(&Bs[row][c * 8]) =
          *reinterpret_cast<const int4*>(Wb + (size_t)(n0 + row) * E_ + k0 + c * 8);
    }
    __syncthreads();
    bf16x8 af[4], bfr[4];
#pragma unroll
    for (int i = 0; i < 4; ++i)
      af[i] = *reinterpret_cast<const bf16x8*>(&As[wr * 64 + i * 16 + lo][hi * 8]);
#pragma unroll
    for (int j = 0; j < 4; ++j)
      bfr[j] = *reinterpret_cast<const bf16x8*>(&Bs[wc * 64 + j * 16 + lo][hi * 8]);
#pragma unroll
    for (int i = 0; i < 4; ++i)
#pragma unroll
      for (int j = 0; j < 4; ++j)
        acc[i][j] = __builtin_amdgcn_mfma_f32_16x16x32_bf16(af[i], bfr[j], acc[i][j], 0, 0, 0);
    __syncthreads();
  }
#pragma unroll
  for (int i = 0; i < 4; ++i)
#pragma unroll
    for (int r = 0; r < 4; ++r) {
      int mm = m0 + wr * 64 + i * 16 + hi * 4 + r;
      float* orow = out + (size_t)mm * E_ + n0 + wc * 64;
#pragma unroll
      for (int j = 0; j < 4; ++j)
        orow[j * 16 + lo] = acc[i][j][r] + bias[n0 + wc * 64 + j * 16 + lo];
    }
}

extern "C" void kernel_launch(void* const* d_in, const int* in_sizes, int n_in,
                              void* d_out, int out_size, void* d_ws, size_t ws_size,
                              hipStream_t stream) {
  (void)in_sizes; (void)n_in; (void)out_size; (void)ws_size;
  const float* x  = (const float*)d_in[0];
  const float* Wq = (const float*)d_in[1];
  const float* bq = (const float*)d_in[2];
  const float* Wp = (const float*)d_in[3];
  const float* bp = (const float*)d_in[4];
  float* out = (float*)d_out;

  // workspace layout (ushort elements):
  // Q,K,V: [B,H,T,HD] bf16 (8388608 each) | AO: [B,T,H,HD] bf16 | Wt: [H,192,HD] | Wb: [E,E]
  const size_t NQ = (size_t)B_ * H_ * T_ * HD_;
  ushort* ws = (ushort*)d_ws;
  ushort* Q  = ws;
  ushort* K  = ws + NQ;
  ushort* V  = ws + 2 * NQ;
  ushort* AO = ws + 3 * NQ;
  ushort* Wb = ws + 4 * NQ;
  ushort* Wt = ws + 4 * NQ + (size_t)E_ * E_;

  cvt_w_kernel<<<dim3(768), dim3(256), 0, stream>>>(Wq, Wt);
  cvt_wproj_kernel<<<dim3(1024), dim3(256), 0, stream>>>(Wp, Wb);
  qkv_kernel<<<dim3(T_ / 64, B_ * H_), dim3(256), 0, stream>>>(x, Wt, bq, Q, K, V);
  attn_kernel<<<dim3(T_ / 64, B_ * H_), dim3(256), 0, stream>>>(Q, K, V, AO);
  proj_kernel<<<dim3(E_ / 128, (B_ * T_) / 128), dim3(256), 0, stream>>>(AO, Wb, bp, out);
}